// Round 1
// baseline (642.698 us; speedup 1.0000x reference)
//
#include <hip/hip_runtime.h>

#define N_NODES 100000
#define N_EDGES 1600000
#define NBLK    391          // ceil(N_NODES/256)

// ---------------- CSR build ----------------

__global__ void k_count(const int* __restrict__ dst, int* __restrict__ cnt) {
    int e = blockIdx.x * 256 + threadIdx.x;
    if (e < N_EDGES) atomicAdd(&cnt[dst[e]], 1);
}

__global__ void k_dinv(const int* __restrict__ cnt, float* __restrict__ dinv) {
    int i = blockIdx.x * 256 + threadIdx.x;
    if (i < N_NODES) dinv[i] = rsqrtf((float)(cnt[i] + 1));   // +1 self-loop
}

__global__ void k_scan1(const int* __restrict__ cnt, int* __restrict__ rp,
                        int* __restrict__ bsum) {
    __shared__ int sh[256];
    int t = threadIdx.x;
    int i = blockIdx.x * 256 + t;
    int v = (i < N_NODES) ? cnt[i] : 0;
    sh[t] = v;
    __syncthreads();
    for (int o = 1; o < 256; o <<= 1) {
        int u = (t >= o) ? sh[t - o] : 0;
        __syncthreads();
        sh[t] += u;
        __syncthreads();
    }
    if (i < N_NODES) rp[i] = sh[t] - v;          // block-local exclusive
    if (t == 255) bsum[blockIdx.x] = sh[t];
}

__global__ void k_scan2(const int* __restrict__ bsum, int* __restrict__ bo, int nb) {
    __shared__ int sh[512];
    int t = threadIdx.x;
    sh[t] = (t < nb) ? bsum[t] : 0;
    __syncthreads();
    for (int o = 1; o < 512; o <<= 1) {
        int u = (t >= o) ? sh[t - o] : 0;
        __syncthreads();
        sh[t] += u;
        __syncthreads();
    }
    if (t <= nb) bo[t] = (t == 0) ? 0 : sh[t - 1];   // bo[nb] = total
}

__global__ void k_scan3(int* __restrict__ rp, const int* __restrict__ bo, int nb) {
    int i = blockIdx.x * 256 + threadIdx.x;
    if (i < N_NODES)      rp[i] += bo[i >> 8];
    else if (i == N_NODES) rp[N_NODES] = bo[nb];
}

__global__ void k_fill(const int* __restrict__ src, const int* __restrict__ dst,
                       const int* __restrict__ rp, int* __restrict__ fill,
                       int* __restrict__ col) {
    int e = blockIdx.x * 256 + threadIdx.x;
    if (e < N_EDGES) {
        int d = dst[e];
        int pos = atomicAdd(&fill[d], 1);
        col[rp[d] + pos] = src[e];
    }
}

// ---------------- dense GEMM (fp32 vector, W in LDS, x via readlane) ----------------

__device__ __forceinline__ float lane_bcast(float v, int l) {
    return __int_as_float(__builtin_amdgcn_readlane(__float_as_int(v), l));
}

template <int NOUT>
__global__ __launch_bounds__(256) void k_gemm(const float* __restrict__ X,
                                              const float* __restrict__ W,
                                              float* __restrict__ H) {
    __shared__ float sw[128 * NOUT];
    for (int i = threadIdx.x; i < 128 * NOUT / 4; i += 256)
        reinterpret_cast<float4*>(sw)[i] = reinterpret_cast<const float4*>(W)[i];
    __syncthreads();

    int wv = threadIdx.x >> 6, lane = threadIdx.x & 63;
    int row0 = blockIdx.x * 16 + wv * 4;   // N_NODES = 16*6250, always in range

    float xr[4][2];
#pragma unroll
    for (int r = 0; r < 4; r++) {
        const float* xp = X + (size_t)(row0 + r) * 128;
        xr[r][0] = xp[lane];
        xr[r][1] = xp[64 + lane];
    }

    float acc[4][2] = {{0.f, 0.f}, {0.f, 0.f}, {0.f, 0.f}, {0.f, 0.f}};
#pragma unroll
    for (int k = 0; k < 128; k++) {
        float w0 = sw[k * NOUT + lane];
        float w1 = (NOUT == 128) ? sw[k * NOUT + lane + 64] : 0.0f;
#pragma unroll
        for (int r = 0; r < 4; r++) {
            float xv = lane_bcast(xr[r][k >> 6], k & 63);
            acc[r][0] += xv * w0;
            if (NOUT == 128) acc[r][1] += xv * w1;
        }
    }
#pragma unroll
    for (int r = 0; r < 4; r++) {
        float* hp = H + (size_t)(row0 + r) * NOUT;
        hp[lane] = acc[r][0];
        if (NOUT == 128) hp[lane + 64] = acc[r][1];
    }
}

// ---------------- gather aggregation (one wave per node) ----------------

template <int NF, bool RELU>
__global__ __launch_bounds__(256) void k_agg(const float* __restrict__ H,
                                             const float* __restrict__ dinv,
                                             const int* __restrict__ rp,
                                             const int* __restrict__ col,
                                             const float* __restrict__ bias,
                                             float* __restrict__ out) {
    int gw = (blockIdx.x * 256 + threadIdx.x) >> 6;   // node index (1 wave/node)
    int lane = threadIdx.x & 63;
    if (gw >= N_NODES) return;

    float di = dinv[gw];
    int e0 = rp[gw], e1 = rp[gw + 1];

    float a0, a1 = 0.f;
    if (NF == 128) {
        float2 v = *reinterpret_cast<const float2*>(H + (size_t)gw * 128 + 2 * lane);
        a0 = v.x * di * di;
        a1 = v.y * di * di;
    } else {
        a0 = H[(size_t)gw * 64 + lane] * di * di;
    }

    for (int e = e0; e < e1; e++) {
        int s = __builtin_amdgcn_readfirstlane(col[e]);
        float w = dinv[s] * di;
        if (NF == 128) {
            float2 v = *reinterpret_cast<const float2*>(H + (size_t)s * 128 + 2 * lane);
            a0 += v.x * w;
            a1 += v.y * w;
        } else {
            a0 += H[(size_t)s * 64 + lane] * w;
        }
    }

    if (NF == 128) {
        a0 += bias[2 * lane];
        a1 += bias[2 * lane + 1];
        if (RELU) { a0 = fmaxf(a0, 0.f); a1 = fmaxf(a1, 0.f); }
        float2 r{a0, a1};
        *reinterpret_cast<float2*>(out + (size_t)gw * 128 + 2 * lane) = r;
    } else {
        a0 += bias[lane];
        if (RELU) a0 = fmaxf(a0, 0.f);
        out[(size_t)gw * 64 + lane] = a0;
    }
}

// ---------------- launch ----------------

extern "C" void kernel_launch(void* const* d_in, const int* in_sizes, int n_in,
                              void* d_out, int out_size, void* d_ws, size_t ws_size,
                              hipStream_t stream) {
    const float* x  = (const float*)d_in[0];
    const int*   ei = (const int*)d_in[1];     // [2, E] int32
    const float* W1 = (const float*)d_in[2];
    const float* b1 = (const float*)d_in[3];
    const float* W2 = (const float*)d_in[4];
    const float* b2 = (const float*)d_in[5];
    float* out = (float*)d_out;

    const int* src = ei;
    const int* dst = ei + N_EDGES;

    char* ws = (char*)d_ws;
    size_t off = 0;
    auto alloc = [&](size_t bytes) -> void* {
        off = (off + 255) & ~(size_t)255;
        void* p = ws + off;
        off += bytes;
        return p;
    };
    int*   cnt  = (int*)alloc((size_t)N_NODES * 4);
    int*   fill = (int*)alloc((size_t)N_NODES * 4);
    int*   rp   = (int*)alloc((size_t)(N_NODES + 1) * 4);
    int*   bsum = (int*)alloc((size_t)NBLK * 4);
    int*   bo   = (int*)alloc((size_t)(NBLK + 1) * 4);
    float* dinv = (float*)alloc((size_t)N_NODES * 4);
    int*   col  = (int*)alloc((size_t)N_EDGES * 4);
    float* h1   = (float*)alloc((size_t)N_NODES * 128 * 4);
    float* h2   = (float*)alloc((size_t)N_NODES * 128 * 4);
    float* h3   = h1;   // h1 is dead after layer-1 aggregation; reuse for h2@W2

    hipMemsetAsync(cnt, 0, (size_t)N_NODES * 4, stream);
    hipMemsetAsync(fill, 0, (size_t)N_NODES * 4, stream);

    int ebl = (N_EDGES + 255) / 256;
    int nbl = (N_NODES + 255) / 256;

    // CSR build (shared by both layers)
    k_count<<<ebl, 256, 0, stream>>>(dst, cnt);
    k_dinv<<<nbl, 256, 0, stream>>>(cnt, dinv);
    k_scan1<<<NBLK, 256, 0, stream>>>(cnt, rp, bsum);
    k_scan2<<<1, 512, 0, stream>>>(bsum, bo, NBLK);
    k_scan3<<<(N_NODES + 1 + 255) / 256, 256, 0, stream>>>(rp, bo, NBLK);
    k_fill<<<ebl, 256, 0, stream>>>(src, dst, rp, fill, col);

    // layer 1: h1 = x@W1 ; h2 = relu(agg(h1) + b1)
    k_gemm<128><<<N_NODES / 16, 256, 0, stream>>>(x, W1, h1);
    k_agg<128, true><<<(N_NODES + 3) / 4, 256, 0, stream>>>(h1, dinv, rp, col, b1, h2);

    // layer 2: h3 = h2@W2 ; out = agg(h3) + b2
    k_gemm<64><<<N_NODES / 16, 256, 0, stream>>>(h2, W2, h3);
    k_agg<64, false><<<(N_NODES + 3) / 4, 256, 0, stream>>>(h3, dinv, rp, col, b2, out);
}